// Round 4
// baseline (323.234 us; speedup 1.0000x reference)
//
#include <hip/hip_runtime.h>
#include <hip/hip_bf16.h>
#include <cstdint>
#include <cstddef>

#define N_NODES 50000
#define N_EDGES 640000
#define ET (N_EDGES + N_NODES)   // 690000 with self loops
#define IN_CH 128
#define H1 4
#define HC1 256                  // H1*C1
#define OUT_CH 64
#define SLOPE 0.2f
#define SCAN_NBLK ((N_NODES + 255) / 256)   // 196
#define XW (N_NODES * IN_CH / 8)            // 800000
#define W1N (IN_CH * HC1)                   // 32768
#define W2N (HC1 * OUT_CH)                  // 16384
#define CONVB ((XW + W1N + W2N + 255) / 256)  // 3317
#define EDGEB ((ET + 255) / 256)            // 2696
#define MT ((N_NODES + 63) / 64)            // 782
#define G1B (4 * MT)                        // 3128 (round-0 proven tiling)

typedef __attribute__((ext_vector_type(8))) short short8;
typedef __attribute__((ext_vector_type(4))) float floatx4;

__device__ __forceinline__ float bf2f(unsigned short u) {
    return __uint_as_float(((unsigned)u) << 16);
}
__device__ __forceinline__ unsigned short f2bf(float f) {
    unsigned u = __float_as_uint(f);
    unsigned r = 0x7fffu + ((u >> 16) & 1u);
    return (unsigned short)((u + r) >> 16);
}
__device__ __forceinline__ float ldf(const void* p, size_t i, bool f32) {
    return f32 ? ((const float*)p)[i] : bf2f(((const unsigned short*)p)[i]);
}
#define BLO(u) __uint_as_float((u) << 16)
#define BHI(u) __uint_as_float((u) & 0xffff0000u)

// ---------------- init: zero counts/state + detect dtype ----------------
__global__ __launch_bounds__(256) void init_all(
    const unsigned short* __restrict__ x, unsigned* __restrict__ flag,
    int* __restrict__ counts, int* __restrict__ state)
{
    int b = blockIdx.x;
    if (b < SCAN_NBLK) {
        int i = b * 256 + threadIdx.x;
        if (i < N_NODES) counts[i] = 0;
    } else {
        int t = threadIdx.x;
        if (t < 64) {
            int bad = 0;
            #pragma unroll
            for (int r = 0; r < 4; ++r) {
                float v = bf2f(x[r * 64 + t]);
                if (!(v == v) || fabsf(v) > 1e4f) bad = 1;
            }
            unsigned long long m = __ballot(bad != 0);
            if (t == 0) *flag = (m != 0ull) ? 1u : 0u;
        } else if (t == 64) {
            state[0] = 0; state[1] = 0;
        }
    }
}

// ---------------- conv (x->bf16, W1^T, W2^T) || count edges (+record slot) ----
__global__ __launch_bounds__(256) void conv_count(
    const void* __restrict__ x, const void* __restrict__ W1,
    const void* __restrict__ W2, const unsigned* __restrict__ flag,
    unsigned short* __restrict__ x16,
    unsigned short* __restrict__ Wt1, unsigned short* __restrict__ Wt2,
    const int* __restrict__ edst, int* __restrict__ counts,
    int* __restrict__ epos)
{
    int b = blockIdx.x;
    if (b < CONVB) {
        int i = b * 256 + threadIdx.x;
        const bool f32 = (*flag != 0);
        if (i < XW) {
            size_t off = (size_t)i * 8;
            uint4 st;
            if (f32) {
                const float* xp = (const float*)x + off;
                float4 a = *(const float4*)xp;
                float4 c = *(const float4*)(xp + 4);
                st.x = (unsigned)f2bf(a.x) | ((unsigned)f2bf(a.y) << 16);
                st.y = (unsigned)f2bf(a.z) | ((unsigned)f2bf(a.w) << 16);
                st.z = (unsigned)f2bf(c.x) | ((unsigned)f2bf(c.y) << 16);
                st.w = (unsigned)f2bf(c.z) | ((unsigned)f2bf(c.w) << 16);
            } else {
                st = *(const uint4*)((const unsigned short*)x + off);
            }
            *(uint4*)(x16 + off) = st;
        } else if (i < XW + W1N) {
            int j = i - XW;                       // Wt1[n][k] = W1[k][n]
            int n = j / IN_CH, k = j % IN_CH;
            Wt1[j] = f2bf(ldf(W1, (size_t)k * HC1 + n, f32));
        } else if (i < XW + W1N + W2N) {
            int j = i - XW - W1N;                 // Wt2[n][k] = W2[k][n]
            int n = j / HC1, k = j % HC1;
            Wt2[j] = f2bf(ldf(W2, (size_t)k * OUT_CH + n, f32));
        }
    } else {
        int i = (b - CONVB) * 256 + threadIdx.x;
        if (i < ET) {
            int d = (i < N_EDGES) ? edst[i] : (i - N_EDGES);
            epos[i] = atomicAdd(&counts[d], 1);   // slot within bucket
        }
    }
}

// ---------------- single-dispatch two-phase scan (exact counts) --------------
__global__ __launch_bounds__(256) void scan_onepass(
    const int* __restrict__ counts, int* __restrict__ rowptr,
    int* __restrict__ bsum, int* __restrict__ boff, int* __restrict__ state)
{
    __shared__ int s[256];
    const int t = threadIdx.x, b = blockIdx.x;
    const int i = b * 256 + t;
    int v = (i < N_NODES) ? counts[i] : 0;
    s[t] = v;
    __syncthreads();
    #pragma unroll
    for (int off = 1; off < 256; off <<= 1) {
        int u = (t >= off) ? s[t - off] : 0;
        __syncthreads();
        s[t] += u;
        __syncthreads();
    }
    const int incl = s[t];
    if (t == 255) {
        __hip_atomic_store(&bsum[b], incl, __ATOMIC_RELAXED, __HIP_MEMORY_SCOPE_AGENT);
        __hip_atomic_fetch_add(&state[0], 1, __ATOMIC_ACQ_REL, __HIP_MEMORY_SCOPE_AGENT);
    }
    if (b == 0) {
        if (t == 0) {
            while (__hip_atomic_load(&state[0], __ATOMIC_ACQUIRE, __HIP_MEMORY_SCOPE_AGENT) < SCAN_NBLK)
                __builtin_amdgcn_s_sleep(8);
        }
        __syncthreads();
        int w = (t < SCAN_NBLK)
              ? __hip_atomic_load(&bsum[t], __ATOMIC_RELAXED, __HIP_MEMORY_SCOPE_AGENT) : 0;
        s[t] = w;
        __syncthreads();
        #pragma unroll
        for (int off = 1; off < 256; off <<= 1) {
            int u = (t >= off) ? s[t - off] : 0;
            __syncthreads();
            s[t] += u;
            __syncthreads();
        }
        if (t < SCAN_NBLK)
            __hip_atomic_store(&boff[t], s[t] - w, __ATOMIC_RELAXED, __HIP_MEMORY_SCOPE_AGENT);
        __syncthreads();
        if (t == 0)
            __hip_atomic_store(&state[1], 1, __ATOMIC_RELEASE, __HIP_MEMORY_SCOPE_AGENT);
    }
    if (t == 0) {
        while (__hip_atomic_load(&state[1], __ATOMIC_ACQUIRE, __HIP_MEMORY_SCOPE_AGENT) == 0)
            __builtin_amdgcn_s_sleep(8);
    }
    __syncthreads();
    int off0 = __hip_atomic_load(&boff[b], __ATOMIC_RELAXED, __HIP_MEMORY_SCOPE_AGENT);
    if (i < N_NODES)
        rowptr[i] = off0 + incl - v;   // exclusive
    if (i == N_NODES - 1) rowptr[N_NODES] = off0 + incl;   // == ET
}

// ---------------- MFMA bf16 GEMM body (round-0 proven: NSUB=4) --------
template <int KK, int NSUB>
__device__ __forceinline__ void gemm_body(
    const unsigned short* __restrict__ A, const unsigned short* __restrict__ Bt,
    const void* __restrict__ avs, const void* __restrict__ avd,
    const unsigned* __restrict__ flag, unsigned short* __restrict__ C,
    float* __restrict__ als, float* __restrict__ ald,
    int M, int N, int bx, int by)
{
    const int tid = threadIdx.x;
    const int m0 = by * 64, n0 = bx * (NSUB * 16);
    const int w = tid >> 6, lane = tid & 63;
    const int ln = lane & 15, quad = lane >> 4;
    const int m_frag = m0 + w * 16 + ln;
    floatx4 acc[NSUB];
    #pragma unroll
    for (int sub = 0; sub < NSUB; ++sub)
        acc[sub] = (floatx4){0.f, 0.f, 0.f, 0.f};

    for (int ks = 0; ks < KK / 32; ++ks) {
        const int kbase = ks * 32 + quad * 8;
        short8 a;
        if (m_frag < M) {
            a = *(const short8*)(A + (size_t)m_frag * KK + kbase);
        } else {
            #pragma unroll
            for (int j = 0; j < 8; ++j) a[j] = 0;
        }
        #pragma unroll
        for (int sub = 0; sub < NSUB; ++sub) {
            short8 b = *(const short8*)(Bt + (size_t)(n0 + sub * 16 + ln) * KK + kbase);
            acc[sub] = __builtin_amdgcn_mfma_f32_16x16x32_bf16(a, b, acc[sub], 0, 0, 0);
        }
    }

    #pragma unroll
    for (int sub = 0; sub < NSUB; ++sub) {
        #pragma unroll
        for (int r = 0; r < 4; ++r) {
            int m = m0 + w * 16 + quad * 4 + r;
            if (m < M)
                C[(size_t)m * N + n0 + sub * 16 + ln] = f2bf(acc[sub][r]);
        }
    }

    const bool f32in = (*flag != 0);
    float as[NSUB], av[NSUB];
    #pragma unroll
    for (int sub = 0; sub < NSUB; ++sub) {
        as[sub] = ldf(avs, n0 + sub * 16 + ln, f32in);
        av[sub] = ldf(avd, n0 + sub * 16 + ln, f32in);
    }
    const int Hh = N >> 6;
    #pragma unroll
    for (int hb = 0; hb < NSUB / 4; ++hb) {
        #pragma unroll
        for (int r = 0; r < 4; ++r) {
            float ps = 0.f, pd = 0.f;
            #pragma unroll
            for (int k = 0; k < 4; ++k) {
                ps += acc[hb * 4 + k][r] * as[hb * 4 + k];
                pd += acc[hb * 4 + k][r] * av[hb * 4 + k];
            }
            #pragma unroll
            for (int off = 1; off < 16; off <<= 1) {
                ps += __shfl_xor(ps, off, 64);
                pd += __shfl_xor(pd, off, 64);
            }
            int m = m0 + w * 16 + quad * 4 + r;
            if (ln == 0 && m < M) {
                als[(size_t)m * Hh + bx * (NSUB / 4) + hb] = ps;
                ald[(size_t)m * Hh + bx * (NSUB / 4) + hb] = pd;
            }
        }
    }
}

// -------- layer-1 GEMM (64x64 tiles) || fill_csr (atomic-free) ---------------
__global__ __launch_bounds__(256) void gemm1_fill(
    const unsigned short* __restrict__ x16, const unsigned short* __restrict__ Wt1,
    const void* __restrict__ as1, const void* __restrict__ ad1,
    const unsigned* __restrict__ flag, unsigned short* __restrict__ h16,
    float* __restrict__ als, float* __restrict__ ald,
    const int* __restrict__ esrc, const int* __restrict__ edst,
    const int* __restrict__ rowptr, const int* __restrict__ epos,
    int* __restrict__ ecsr)
{
    int b = blockIdx.x;
    if (b < G1B) {
        gemm_body<IN_CH, 4>(x16, Wt1, as1, ad1, flag, h16, als, ald,
                            N_NODES, HC1, b & 3, b >> 2);
    } else {
        int i = (b - G1B) * 256 + threadIdx.x;
        if (i < ET) {
            int s = (i < N_EDGES) ? esrc[i] : (i - N_EDGES);
            int d = (i < N_EDGES) ? edst[i] : (i - N_EDGES);
            ecsr[rowptr[d] + epos[i]] = s;   // no atomic: slot recorded in count
        }
    }
}

// -------- per-edge attention weights, layer 1 (head-major planes) ------------
// p[h][slot] = exp(leakyrelu(als1[s][h] + ald1[d][h])). Pure edge-parallel;
// removes the random als gather + exp from the hot gather kernel.
__global__ __launch_bounds__(256) void edge_w1(
    const int* __restrict__ esrc, const int* __restrict__ edst,
    const int* __restrict__ rowptr, const int* __restrict__ epos,
    const float* __restrict__ als1, const float* __restrict__ ald1,
    float* __restrict__ ew1)
{
    int i = blockIdx.x * 256 + threadIdx.x;
    if (i >= ET) return;
    int s = (i < N_EDGES) ? esrc[i] : (i - N_EDGES);
    int d = (i < N_EDGES) ? edst[i] : (i - N_EDGES);
    int slot = rowptr[d] + epos[i];
    float4 as = *(const float4*)(als1 + (size_t)s * H1);
    float4 ad = *(const float4*)(ald1 + (size_t)d * H1);
    float t0 = as.x + ad.x, t1 = as.y + ad.y;
    float t2 = as.z + ad.z, t3 = as.w + ad.w;
    ew1[0 * (size_t)ET + slot] = __expf(fmaxf(t0, SLOPE * t0));
    ew1[1 * (size_t)ET + slot] = __expf(fmaxf(t1, SLOPE * t1));
    ew1[2 * (size_t)ET + slot] = __expf(fmaxf(t2, SLOPE * t2));
    ew1[3 * (size_t)ET + slot] = __expf(fmaxf(t3, SLOPE * t3));
}

// ------- gather-aggregate, layer 1 (H=4): R0 loop shape, precomputed p -------
__global__ __launch_bounds__(256) void agg_node1(
    const int* __restrict__ rowptr, const int* __restrict__ ecsr,
    const unsigned short* __restrict__ h, const float* __restrict__ ew1,
    const void* __restrict__ bias, const unsigned* __restrict__ flag,
    unsigned short* __restrict__ out)
{
    int wave = (blockIdx.x * blockDim.x + threadIdx.x) >> 6;
    int lane = threadIdx.x & 63;
    if (wave >= N_NODES) return;
    const int d = wave;
    const int hg = lane >> 4;          // head
    const int c0 = (lane & 15) << 2;   // channel base (4 channels)
    const int hoff = hg * 64 + c0;
    const int lo = rowptr[d], hi = rowptr[d + 1];
    const float* __restrict__ ewh = ew1 + (size_t)hg * ET;   // my head's plane

    float acc0 = 0.f, acc1 = 0.f, acc2 = 0.f, acc3 = 0.f, den = 0.f;

    int e = lo;
    for (; e + 3 < hi; e += 4) {
        int s0 = ecsr[e], s1 = ecsr[e + 1], s2 = ecsr[e + 2], s3 = ecsr[e + 3];
        float p0 = ewh[e], p1 = ewh[e + 1], p2 = ewh[e + 2], p3 = ewh[e + 3];
        uint2 q0 = *(const uint2*)(h + (size_t)s0 * HC1 + hoff);
        uint2 q1 = *(const uint2*)(h + (size_t)s1 * HC1 + hoff);
        uint2 q2 = *(const uint2*)(h + (size_t)s2 * HC1 + hoff);
        uint2 q3 = *(const uint2*)(h + (size_t)s3 * HC1 + hoff);
        den += (p0 + p1) + (p2 + p3);
        acc0 += p0 * BLO(q0.x) + p1 * BLO(q1.x) + p2 * BLO(q2.x) + p3 * BLO(q3.x);
        acc1 += p0 * BHI(q0.x) + p1 * BHI(q1.x) + p2 * BHI(q2.x) + p3 * BHI(q3.x);
        acc2 += p0 * BLO(q0.y) + p1 * BLO(q1.y) + p2 * BLO(q2.y) + p3 * BLO(q3.y);
        acc3 += p0 * BHI(q0.y) + p1 * BHI(q1.y) + p2 * BHI(q2.y) + p3 * BHI(q3.y);
    }
    for (; e < hi; ++e) {
        int s0 = ecsr[e];
        float p0 = ewh[e];
        uint2 q0 = *(const uint2*)(h + (size_t)s0 * HC1 + hoff);
        den += p0;
        acc0 += p0 * BLO(q0.x);
        acc1 += p0 * BHI(q0.x);
        acc2 += p0 * BLO(q0.y);
        acc3 += p0 * BHI(q0.y);
    }

    const bool f32in = (*flag != 0);
    const float inv = 1.f / den;
    float v0 = acc0 * inv + ldf(bias, hoff + 0, f32in);
    float v1 = acc1 * inv + ldf(bias, hoff + 1, f32in);
    float v2 = acc2 * inv + ldf(bias, hoff + 2, f32in);
    float v3 = acc3 * inv + ldf(bias, hoff + 3, f32in);
    v0 = (v0 > 0.f) ? v0 : (__expf(v0) - 1.f);
    v1 = (v1 > 0.f) ? v1 : (__expf(v1) - 1.f);
    v2 = (v2 > 0.f) ? v2 : (__expf(v2) - 1.f);
    v3 = (v3 > 0.f) ? v3 : (__expf(v3) - 1.f);
    uint2 st;
    st.x = (unsigned)f2bf(v0) | ((unsigned)f2bf(v1) << 16);
    st.y = (unsigned)f2bf(v2) | ((unsigned)f2bf(v3) << 16);
    *(uint2*)(out + (size_t)d * HC1 + hoff) = st;
}

// ---------------- layer-2 GEMM ----------------
__global__ __launch_bounds__(256) void gemm2(
    const unsigned short* __restrict__ xo16, const unsigned short* __restrict__ Wt2,
    const void* __restrict__ as2, const void* __restrict__ ad2,
    const unsigned* __restrict__ flag, unsigned short* __restrict__ h2,
    float* __restrict__ als, float* __restrict__ ald)
{
    gemm_body<HC1, 4>(xo16, Wt2, as2, ad2, flag, h2, als, ald,
                      N_NODES, OUT_CH, 0, blockIdx.x);
}

// ------- fused softmax + gather-aggregate, layer 2 (H=1): R0 proven form -----
__global__ __launch_bounds__(256) void agg_node2(
    const int* __restrict__ rowptr, const int* __restrict__ ecsr,
    const unsigned short* __restrict__ h, const float* __restrict__ als,
    const float* __restrict__ ald, const void* __restrict__ bias,
    const unsigned* __restrict__ flag, float* __restrict__ out)
{
    int wave = (blockIdx.x * blockDim.x + threadIdx.x) >> 6;
    int lane = threadIdx.x & 63;
    if (wave >= N_NODES) return;
    const int d = wave;
    const int eg = lane >> 3;          // edge slot 0..7
    const int c0 = (lane & 7) << 3;    // channel base (8 channels)
    const int lo = rowptr[d], hi = rowptr[d + 1];
    const float ad = ald[d];

    float acc[8];
    #pragma unroll
    for (int j = 0; j < 8; ++j) acc[j] = 0.f;
    float den = 0.f;

    for (int eb = lo; eb < hi; eb += 8) {
        int e = eb + eg;
        if (e < hi) {
            int s = ecsr[e];
            uint4 q = *(const uint4*)(h + (size_t)s * OUT_CH + c0);
            float t = als[s] + ad;
            float p = __expf(fmaxf(t, SLOPE * t));
            den += p;
            acc[0] += p * BLO(q.x);
            acc[1] += p * BHI(q.x);
            acc[2] += p * BLO(q.y);
            acc[3] += p * BHI(q.y);
            acc[4] += p * BLO(q.z);
            acc[5] += p * BHI(q.z);
            acc[6] += p * BLO(q.w);
            acc[7] += p * BHI(q.w);
        }
    }
    #pragma unroll
    for (int off = 8; off <= 32; off <<= 1) {
        den += __shfl_xor(den, off, 64);
        #pragma unroll
        for (int j = 0; j < 8; ++j) acc[j] += __shfl_xor(acc[j], off, 64);
    }
    if (lane < 8) {
        const bool f32in = (*flag != 0);
        const float inv = 1.f / den;
        float4 v0, v1;
        v0.x = acc[0] * inv + ldf(bias, c0 + 0, f32in);
        v0.y = acc[1] * inv + ldf(bias, c0 + 1, f32in);
        v0.z = acc[2] * inv + ldf(bias, c0 + 2, f32in);
        v0.w = acc[3] * inv + ldf(bias, c0 + 3, f32in);
        v1.x = acc[4] * inv + ldf(bias, c0 + 4, f32in);
        v1.y = acc[5] * inv + ldf(bias, c0 + 5, f32in);
        v1.z = acc[6] * inv + ldf(bias, c0 + 6, f32in);
        v1.w = acc[7] * inv + ldf(bias, c0 + 7, f32in);
        *(float4*)(out + (size_t)d * OUT_CH + c0) = v0;
        *(float4*)(out + (size_t)d * OUT_CH + c0 + 4) = v1;
    }
}

extern "C" void kernel_launch(void* const* d_in, const int* in_sizes, int n_in,
                              void* d_out, int out_size, void* d_ws, size_t ws_size,
                              hipStream_t stream)
{
    const void* x   = d_in[0];
    const void* W1  = d_in[1];
    const void* as1 = d_in[2];
    const void* ad1 = d_in[3];
    const void* b1  = d_in[4];
    const void* W2  = d_in[5];
    const void* as2 = d_in[6];
    const void* ad2 = d_in[7];
    const void* b2  = d_in[8];
    const int* esrc = (const int*)d_in[9];
    const int* edst = (const int*)d_in[10];
    float* out = (float*)d_out;  // [N,64] float32

    char* base = (char*)d_ws;
    const size_t MB = 1024 * 1024;
    unsigned short* x16  = (unsigned short*)(base);            // 12.8 MB [N,128] bf16
    float* ew1           = (float*)(base);                     // 11.0 MB, overlays x16
                                                               // (x16 dead after gemm1)
    unsigned short* h16  = (unsigned short*)(base + 13 * MB);  // 25.6 MB h1 [N,256] bf16
    unsigned short* xo16 = (unsigned short*)(base + 39 * MB);  // 25.6 MB x2 [N,256] bf16
    unsigned short* h2   = (unsigned short*)(base + 65 * MB);  //  6.4 MB h2 [N,64] bf16
    float* als1   = (float*)(base + 72 * MB);                  // 800 KB
    float* ald1   = (float*)(base + 73 * MB);                  // 800 KB
    float* als2   = (float*)(base + 74 * MB);                  // 200 KB
    float* ald2   = (float*)(base + 74 * MB + 512 * 1024);     // 200 KB
    unsigned short* Wt1 = (unsigned short*)(base + 75 * MB);   // 64 KB [256][128]
    unsigned short* Wt2 = (unsigned short*)(base + 75 * MB + 128 * 1024); // 32 KB
    int* counts   = (int*)(base + 76 * MB);                    // 200 KB
    int* rowptr   = (int*)(base + 77 * MB);                    // 200 KB + 4 B
    int* bsum     = (int*)(base + 78 * MB);                    // small
    int* boff     = bsum + 256;
    int* state    = boff + 256;
    unsigned* flag = (unsigned*)(base + 78 * MB + 8 * 1024);
    int* epos     = (int*)(base + 79 * MB);                    // 2.76 MB
    int* ecsr     = (int*)(base + 82 * MB);                    // 2.76 MB (exact)

    const int BLK = 256;
    const int node_wave_blocks = (N_NODES * 64 + BLK - 1) / BLK;  // 12500

    // 1. init: zero counts/state + detect dtype
    init_all<<<SCAN_NBLK + 1, BLK, 0, stream>>>(
        (const unsigned short*)x, flag, counts, state);

    // 2. conv (x16, Wt1, Wt2) || count edges (records per-edge slot in epos)
    conv_count<<<CONVB + EDGEB, BLK, 0, stream>>>(
        x, W1, W2, flag, x16, Wt1, Wt2, edst, counts, epos);

    // 3. single-dispatch scan (exact counts) -> rowptr
    scan_onepass<<<SCAN_NBLK, BLK, 0, stream>>>(
        counts, rowptr, bsum, boff, state);

    // 4. layer-1 GEMM (64x64 tiles) || fill_csr
    gemm1_fill<<<G1B + EDGEB, BLK, 0, stream>>>(
        x16, Wt1, as1, ad1, flag, h16, als1, ald1, esrc, edst, rowptr, epos,
        ecsr);

    // 5. per-edge attention weights, layer 1 (ew1 overlays dead x16)
    edge_w1<<<EDGEB, BLK, 0, stream>>>(
        esrc, edst, rowptr, epos, als1, ald1, ew1);

    // 6. layer-1 aggregate (precomputed p)
    agg_node1<<<node_wave_blocks, BLK, 0, stream>>>(
        rowptr, ecsr, h16, ew1, b1, flag, xo16);

    // 7. layer-2 GEMM
    gemm2<<<MT, BLK, 0, stream>>>(xo16, Wt2, as2, ad2, flag, h2, als2, ald2);

    // 8. layer-2 aggregate -> out
    agg_node2<<<node_wave_blocks, BLK, 0, stream>>>(
        rowptr, ecsr, h2, als2, ald2, b2, flag, out);
}

// Round 5
// 296.777 us; speedup vs baseline: 1.0891x; 1.0891x over previous
//
#include <hip/hip_runtime.h>
#include <hip/hip_bf16.h>
#include <cstdint>
#include <cstddef>

#define N_NODES 50000
#define N_EDGES 640000
#define ET (N_EDGES + N_NODES)   // 690000 with self loops
#define IN_CH 128
#define H1 4
#define HC1 256                  // H1*C1
#define OUT_CH 64
#define SLOPE 0.2f
#define SCAN_NBLK ((N_NODES + 255) / 256)   // 196
#define XW (N_NODES * IN_CH / 8)            // 800000
#define W1N (IN_CH * HC1)                   // 32768
#define W2N (HC1 * OUT_CH)                  // 16384
#define CONVB ((XW + W1N + W2N + 255) / 256)  // 3317
#define EDGEB ((ET + 255) / 256)            // 2696
#define MT ((N_NODES + 63) / 64)            // 782
#define G1B (2 * MT)                        // 1564: NSUB=8 tiles (64x128)

typedef __attribute__((ext_vector_type(8))) short short8;
typedef __attribute__((ext_vector_type(4))) float floatx4;

__device__ __forceinline__ float bf2f(unsigned short u) {
    return __uint_as_float(((unsigned)u) << 16);
}
__device__ __forceinline__ unsigned short f2bf(float f) {
    unsigned u = __float_as_uint(f);
    unsigned r = 0x7fffu + ((u >> 16) & 1u);
    return (unsigned short)((u + r) >> 16);
}
__device__ __forceinline__ float ldf(const void* p, size_t i, bool f32) {
    return f32 ? ((const float*)p)[i] : bf2f(((const unsigned short*)p)[i]);
}
#define BLO(u) __uint_as_float((u) << 16)
#define BHI(u) __uint_as_float((u) & 0xffff0000u)

// x dtype probe: every wave checks x[0..255] interpreted as bf16; garbage/huge
// values mean the buffer is really f32. Wave-uniform, no global dependency.
__device__ __forceinline__ bool probe_f32(const unsigned short* x) {
    int t = threadIdx.x & 63;
    int bad = 0;
    #pragma unroll
    for (int r = 0; r < 4; ++r) {
        float v = bf2f(x[r * 64 + t]);
        if (!(v == v) || fabsf(v) > 1e4f) bad = 1;
    }
    unsigned long long m = __ballot(bad != 0);
    return m != 0ull;
}

// ------- conv (x->bf16, W1^T, W2^T) || count edges (+record slot) ------------
// flag detect folded in: each block probes locally; block 0 publishes.
__global__ __launch_bounds__(256) void conv_count(
    const void* __restrict__ x, const void* __restrict__ W1,
    const void* __restrict__ W2, unsigned* __restrict__ flag,
    unsigned short* __restrict__ x16,
    unsigned short* __restrict__ Wt1, unsigned short* __restrict__ Wt2,
    const int* __restrict__ edst, int* __restrict__ counts,
    int* __restrict__ epos)
{
    int b = blockIdx.x;
    if (b < CONVB) {
        const bool f32 = probe_f32((const unsigned short*)x);
        if (b == 0 && threadIdx.x == 0) *flag = f32 ? 1u : 0u;
        int i = b * 256 + threadIdx.x;
        if (i < XW) {
            size_t off = (size_t)i * 8;
            uint4 st;
            if (f32) {
                const float* xp = (const float*)x + off;
                float4 a = *(const float4*)xp;
                float4 c = *(const float4*)(xp + 4);
                st.x = (unsigned)f2bf(a.x) | ((unsigned)f2bf(a.y) << 16);
                st.y = (unsigned)f2bf(a.z) | ((unsigned)f2bf(a.w) << 16);
                st.z = (unsigned)f2bf(c.x) | ((unsigned)f2bf(c.y) << 16);
                st.w = (unsigned)f2bf(c.z) | ((unsigned)f2bf(c.w) << 16);
            } else {
                st = *(const uint4*)((const unsigned short*)x + off);
            }
            *(uint4*)(x16 + off) = st;
        } else if (i < XW + W1N) {
            int j = i - XW;                       // Wt1[n][k] = W1[k][n]
            int n = j / IN_CH, k = j % IN_CH;
            Wt1[j] = f2bf(ldf(W1, (size_t)k * HC1 + n, f32));
        } else if (i < XW + W1N + W2N) {
            int j = i - XW - W1N;                 // Wt2[n][k] = W2[k][n]
            int n = j / HC1, k = j % HC1;
            Wt2[j] = f2bf(ldf(W2, (size_t)k * OUT_CH + n, f32));
        }
    } else {
        int i = (b - CONVB) * 256 + threadIdx.x;
        if (i < ET) {
            int d = (i < N_EDGES) ? edst[i] : (i - N_EDGES);
            epos[i] = atomicAdd(&counts[d], 1);   // slot within bucket
        }
    }
}

// ---------------- MFMA bf16 GEMM body ----------------
template <int KK, int NSUB>
__device__ __forceinline__ void gemm_body(
    const unsigned short* __restrict__ A, const unsigned short* __restrict__ Bt,
    const void* __restrict__ avs, const void* __restrict__ avd,
    const unsigned* __restrict__ flag, unsigned short* __restrict__ C,
    float* __restrict__ als, float* __restrict__ ald,
    int M, int N, int bx, int by)
{
    const int tid = threadIdx.x;
    const int m0 = by * 64, n0 = bx * (NSUB * 16);
    const int w = tid >> 6, lane = tid & 63;
    const int ln = lane & 15, quad = lane >> 4;
    const int m_frag = m0 + w * 16 + ln;
    floatx4 acc[NSUB];
    #pragma unroll
    for (int sub = 0; sub < NSUB; ++sub)
        acc[sub] = (floatx4){0.f, 0.f, 0.f, 0.f};

    for (int ks = 0; ks < KK / 32; ++ks) {
        const int kbase = ks * 32 + quad * 8;
        short8 a;
        if (m_frag < M) {
            a = *(const short8*)(A + (size_t)m_frag * KK + kbase);
        } else {
            #pragma unroll
            for (int j = 0; j < 8; ++j) a[j] = 0;
        }
        #pragma unroll
        for (int sub = 0; sub < NSUB; ++sub) {
            short8 b = *(const short8*)(Bt + (size_t)(n0 + sub * 16 + ln) * KK + kbase);
            acc[sub] = __builtin_amdgcn_mfma_f32_16x16x32_bf16(a, b, acc[sub], 0, 0, 0);
        }
    }

    #pragma unroll
    for (int sub = 0; sub < NSUB; ++sub) {
        #pragma unroll
        for (int r = 0; r < 4; ++r) {
            int m = m0 + w * 16 + quad * 4 + r;
            if (m < M)
                C[(size_t)m * N + n0 + sub * 16 + ln] = f2bf(acc[sub][r]);
        }
    }

    const bool f32in = (*flag != 0);
    float as[NSUB], av[NSUB];
    #pragma unroll
    for (int sub = 0; sub < NSUB; ++sub) {
        as[sub] = ldf(avs, n0 + sub * 16 + ln, f32in);
        av[sub] = ldf(avd, n0 + sub * 16 + ln, f32in);
    }
    const int Hh = N >> 6;
    #pragma unroll
    for (int hb = 0; hb < NSUB / 4; ++hb) {
        #pragma unroll
        for (int r = 0; r < 4; ++r) {
            float ps = 0.f, pd = 0.f;
            #pragma unroll
            for (int k = 0; k < 4; ++k) {
                ps += acc[hb * 4 + k][r] * as[hb * 4 + k];
                pd += acc[hb * 4 + k][r] * av[hb * 4 + k];
            }
            #pragma unroll
            for (int off = 1; off < 16; off <<= 1) {
                ps += __shfl_xor(ps, off, 64);
                pd += __shfl_xor(pd, off, 64);
            }
            int m = m0 + w * 16 + quad * 4 + r;
            if (ln == 0 && m < M) {
                als[(size_t)m * Hh + bx * (NSUB / 4) + hb] = ps;
                ald[(size_t)m * Hh + bx * (NSUB / 4) + hb] = pd;
            }
        }
    }
}

// ---- fused: scan (blocks [0,196)) || layer-1 GEMM || fill_csr (waits) -------
// Scan uses the proven two-phase protocol; rowptr stores are agent-scope
// atomics and state[2] counts finished scan blocks so fill can proceed
// within the same dispatch. Scan blocks are the first 196 dispatched ->
// always resident -> no deadlock.
__global__ __launch_bounds__(256) void gemm1_scan_fill(
    const int* __restrict__ counts, int* __restrict__ rowptr,
    int* __restrict__ bsum, int* __restrict__ boff, int* __restrict__ state,
    const unsigned short* __restrict__ x16, const unsigned short* __restrict__ Wt1,
    const void* __restrict__ as1, const void* __restrict__ ad1,
    const unsigned* __restrict__ flag, unsigned short* __restrict__ h16,
    float* __restrict__ als, float* __restrict__ ald,
    const int* __restrict__ esrc, const int* __restrict__ edst,
    const int* __restrict__ epos, int* __restrict__ ecsr)
{
    const int b = blockIdx.x;
    const int t = threadIdx.x;
    if (b < SCAN_NBLK) {
        __shared__ int s[256];
        const int i = b * 256 + t;
        int v = (i < N_NODES) ? counts[i] : 0;
        s[t] = v;
        __syncthreads();
        #pragma unroll
        for (int off = 1; off < 256; off <<= 1) {
            int u = (t >= off) ? s[t - off] : 0;
            __syncthreads();
            s[t] += u;
            __syncthreads();
        }
        const int incl = s[t];
        if (t == 255) {
            __hip_atomic_store(&bsum[b], incl, __ATOMIC_RELAXED, __HIP_MEMORY_SCOPE_AGENT);
            __hip_atomic_fetch_add(&state[0], 1, __ATOMIC_ACQ_REL, __HIP_MEMORY_SCOPE_AGENT);
        }
        if (b == 0) {
            if (t == 0) {
                while (__hip_atomic_load(&state[0], __ATOMIC_ACQUIRE, __HIP_MEMORY_SCOPE_AGENT) < SCAN_NBLK)
                    __builtin_amdgcn_s_sleep(8);
            }
            __syncthreads();
            int w = (t < SCAN_NBLK)
                  ? __hip_atomic_load(&bsum[t], __ATOMIC_RELAXED, __HIP_MEMORY_SCOPE_AGENT) : 0;
            s[t] = w;
            __syncthreads();
            #pragma unroll
            for (int off = 1; off < 256; off <<= 1) {
                int u = (t >= off) ? s[t - off] : 0;
                __syncthreads();
                s[t] += u;
                __syncthreads();
            }
            if (t < SCAN_NBLK)
                __hip_atomic_store(&boff[t], s[t] - w, __ATOMIC_RELAXED, __HIP_MEMORY_SCOPE_AGENT);
            __syncthreads();
            if (t == 0)
                __hip_atomic_store(&state[1], 1, __ATOMIC_RELEASE, __HIP_MEMORY_SCOPE_AGENT);
        }
        if (t == 0) {
            while (__hip_atomic_load(&state[1], __ATOMIC_ACQUIRE, __HIP_MEMORY_SCOPE_AGENT) == 0)
                __builtin_amdgcn_s_sleep(8);
        }
        __syncthreads();
        int off0 = __hip_atomic_load(&boff[b], __ATOMIC_RELAXED, __HIP_MEMORY_SCOPE_AGENT);
        if (i < N_NODES)
            __hip_atomic_store(&rowptr[i], off0 + incl - v,
                               __ATOMIC_RELAXED, __HIP_MEMORY_SCOPE_AGENT);
        if (i == N_NODES - 1)
            __hip_atomic_store(&rowptr[N_NODES], off0 + incl,
                               __ATOMIC_RELAXED, __HIP_MEMORY_SCOPE_AGENT);
        __syncthreads();
        if (t == 0)
            __hip_atomic_fetch_add(&state[2], 1, __ATOMIC_ACQ_REL, __HIP_MEMORY_SCOPE_AGENT);
    } else if (b < SCAN_NBLK + G1B) {
        int g = b - SCAN_NBLK;
        gemm_body<IN_CH, 8>(x16, Wt1, as1, ad1, flag, h16, als, ald,
                            N_NODES, HC1, g & 1, g >> 1);
    } else {
        if (t == 0) {
            while (__hip_atomic_load(&state[2], __ATOMIC_ACQUIRE, __HIP_MEMORY_SCOPE_AGENT) < SCAN_NBLK)
                __builtin_amdgcn_s_sleep(8);
        }
        __syncthreads();
        int i = (b - SCAN_NBLK - G1B) * 256 + t;
        if (i < ET) {
            int s = (i < N_EDGES) ? esrc[i] : (i - N_EDGES);
            int d = (i < N_EDGES) ? edst[i] : (i - N_EDGES);
            int rp = __hip_atomic_load(&rowptr[d], __ATOMIC_RELAXED, __HIP_MEMORY_SCOPE_AGENT);
            ecsr[rp + epos[i]] = s;   // no atomic: slot recorded in count pass
        }
    }
}

// ------- fused softmax + gather-aggregate, layer 1 (H=4) ---------------------
// R0 proven loop shape; tail removed via clamped index + p=0 select.
__global__ __launch_bounds__(256) void agg_node1(
    const int* __restrict__ rowptr, const int* __restrict__ ecsr,
    const unsigned short* __restrict__ h, const float* __restrict__ als,
    const float* __restrict__ ald, const void* __restrict__ bias,
    const unsigned* __restrict__ flag, unsigned short* __restrict__ out)
{
    int wave = (blockIdx.x * blockDim.x + threadIdx.x) >> 6;
    int lane = threadIdx.x & 63;
    if (wave >= N_NODES) return;
    const int d = wave;
    const int hg = lane >> 4;          // head
    const int c0 = (lane & 15) << 2;   // channel base (4 channels)
    const int hoff = hg * 64 + c0;
    const int lo = rowptr[d], hi = rowptr[d + 1];   // hi > lo (self loop)
    const float ad = ald[d * H1 + hg];

    float acc0 = 0.f, acc1 = 0.f, acc2 = 0.f, acc3 = 0.f, den = 0.f;

    for (int e = lo; e < hi; e += 4) {
        int e1 = min(e + 1, hi - 1), e2 = min(e + 2, hi - 1), e3 = min(e + 3, hi - 1);
        int s0 = ecsr[e],  s1 = ecsr[e1], s2 = ecsr[e2], s3 = ecsr[e3];
        float t0 = als[s0 * H1 + hg] + ad;
        float t1 = als[s1 * H1 + hg] + ad;
        float t2 = als[s2 * H1 + hg] + ad;
        float t3 = als[s3 * H1 + hg] + ad;
        uint2 q0 = *(const uint2*)(h + (size_t)s0 * HC1 + hoff);
        uint2 q1 = *(const uint2*)(h + (size_t)s1 * HC1 + hoff);
        uint2 q2 = *(const uint2*)(h + (size_t)s2 * HC1 + hoff);
        uint2 q3 = *(const uint2*)(h + (size_t)s3 * HC1 + hoff);
        float p0 = __expf(fmaxf(t0, SLOPE * t0));
        float p1 = (e + 1 < hi) ? __expf(fmaxf(t1, SLOPE * t1)) : 0.f;
        float p2 = (e + 2 < hi) ? __expf(fmaxf(t2, SLOPE * t2)) : 0.f;
        float p3 = (e + 3 < hi) ? __expf(fmaxf(t3, SLOPE * t3)) : 0.f;
        den += (p0 + p1) + (p2 + p3);
        acc0 += p0 * BLO(q0.x) + p1 * BLO(q1.x) + p2 * BLO(q2.x) + p3 * BLO(q3.x);
        acc1 += p0 * BHI(q0.x) + p1 * BHI(q1.x) + p2 * BHI(q2.x) + p3 * BHI(q3.x);
        acc2 += p0 * BLO(q0.y) + p1 * BLO(q1.y) + p2 * BLO(q2.y) + p3 * BLO(q3.y);
        acc3 += p0 * BHI(q0.y) + p1 * BHI(q1.y) + p2 * BHI(q2.y) + p3 * BHI(q3.y);
    }

    const bool f32in = (*flag != 0);
    const float inv = 1.f / den;
    float v0 = acc0 * inv + ldf(bias, hoff + 0, f32in);
    float v1 = acc1 * inv + ldf(bias, hoff + 1, f32in);
    float v2 = acc2 * inv + ldf(bias, hoff + 2, f32in);
    float v3 = acc3 * inv + ldf(bias, hoff + 3, f32in);
    v0 = (v0 > 0.f) ? v0 : (__expf(v0) - 1.f);
    v1 = (v1 > 0.f) ? v1 : (__expf(v1) - 1.f);
    v2 = (v2 > 0.f) ? v2 : (__expf(v2) - 1.f);
    v3 = (v3 > 0.f) ? v3 : (__expf(v3) - 1.f);
    uint2 st;
    st.x = (unsigned)f2bf(v0) | ((unsigned)f2bf(v1) << 16);
    st.y = (unsigned)f2bf(v2) | ((unsigned)f2bf(v3) << 16);
    *(uint2*)(out + (size_t)d * HC1 + hoff) = st;
}

// ---------------- layer-2 GEMM ----------------
__global__ __launch_bounds__(256) void gemm2(
    const unsigned short* __restrict__ xo16, const unsigned short* __restrict__ Wt2,
    const void* __restrict__ as2, const void* __restrict__ ad2,
    const unsigned* __restrict__ flag, unsigned short* __restrict__ h2,
    float* __restrict__ als, float* __restrict__ ald)
{
    gemm_body<HC1, 4>(xo16, Wt2, as2, ad2, flag, h2, als, ald,
                      N_NODES, OUT_CH, 0, blockIdx.x);
}

// ------- fused softmax + gather-aggregate, layer 2 (H=1): R0 proven form -----
__global__ __launch_bounds__(256) void agg_node2(
    const int* __restrict__ rowptr, const int* __restrict__ ecsr,
    const unsigned short* __restrict__ h, const float* __restrict__ als,
    const float* __restrict__ ald, const void* __restrict__ bias,
    const unsigned* __restrict__ flag, float* __restrict__ out)
{
    int wave = (blockIdx.x * blockDim.x + threadIdx.x) >> 6;
    int lane = threadIdx.x & 63;
    if (wave >= N_NODES) return;
    const int d = wave;
    const int eg = lane >> 3;          // edge slot 0..7
    const int c0 = (lane & 7) << 3;    // channel base (8 channels)
    const int lo = rowptr[d], hi = rowptr[d + 1];
    const float ad = ald[d];

    float acc[8];
    #pragma unroll
    for (int j = 0; j < 8; ++j) acc[j] = 0.f;
    float den = 0.f;

    for (int eb = lo; eb < hi; eb += 8) {
        int e = eb + eg;
        if (e < hi) {
            int s = ecsr[e];
            uint4 q = *(const uint4*)(h + (size_t)s * OUT_CH + c0);
            float t = als[s] + ad;
            float p = __expf(fmaxf(t, SLOPE * t));
            den += p;
            acc[0] += p * BLO(q.x);
            acc[1] += p * BHI(q.x);
            acc[2] += p * BLO(q.y);
            acc[3] += p * BHI(q.y);
            acc[4] += p * BLO(q.z);
            acc[5] += p * BHI(q.z);
            acc[6] += p * BLO(q.w);
            acc[7] += p * BHI(q.w);
        }
    }
    #pragma unroll
    for (int off = 8; off <= 32; off <<= 1) {
        den += __shfl_xor(den, off, 64);
        #pragma unroll
        for (int j = 0; j < 8; ++j) acc[j] += __shfl_xor(acc[j], off, 64);
    }
    if (lane < 8) {
        const bool f32in = (*flag != 0);
        const float inv = 1.f / den;
        float4 v0, v1;
        v0.x = acc[0] * inv + ldf(bias, c0 + 0, f32in);
        v0.y = acc[1] * inv + ldf(bias, c0 + 1, f32in);
        v0.z = acc[2] * inv + ldf(bias, c0 + 2, f32in);
        v0.w = acc[3] * inv + ldf(bias, c0 + 3, f32in);
        v1.x = acc[4] * inv + ldf(bias, c0 + 4, f32in);
        v1.y = acc[5] * inv + ldf(bias, c0 + 5, f32in);
        v1.z = acc[6] * inv + ldf(bias, c0 + 6, f32in);
        v1.w = acc[7] * inv + ldf(bias, c0 + 7, f32in);
        *(float4*)(out + (size_t)d * OUT_CH + c0) = v0;
        *(float4*)(out + (size_t)d * OUT_CH + c0 + 4) = v1;
    }
}

extern "C" void kernel_launch(void* const* d_in, const int* in_sizes, int n_in,
                              void* d_out, int out_size, void* d_ws, size_t ws_size,
                              hipStream_t stream)
{
    const void* x   = d_in[0];
    const void* W1  = d_in[1];
    const void* as1 = d_in[2];
    const void* ad1 = d_in[3];
    const void* b1  = d_in[4];
    const void* W2  = d_in[5];
    const void* as2 = d_in[6];
    const void* ad2 = d_in[7];
    const void* b2  = d_in[8];
    const int* esrc = (const int*)d_in[9];
    const int* edst = (const int*)d_in[10];
    float* out = (float*)d_out;  // [N,64] float32

    char* base = (char*)d_ws;
    const size_t MB = 1024 * 1024;
    unsigned short* x16  = (unsigned short*)(base);            // 12.8 MB [N,128] bf16
    unsigned short* h16  = (unsigned short*)(base + 13 * MB);  // 25.6 MB h1 [N,256] bf16
    unsigned short* xo16 = (unsigned short*)(base + 39 * MB);  // 25.6 MB x2 [N,256] bf16
    unsigned short* h2   = (unsigned short*)(base + 65 * MB);  //  6.4 MB h2 [N,64] bf16
    float* als1   = (float*)(base + 72 * MB);                  // 800 KB
    float* ald1   = (float*)(base + 73 * MB);                  // 800 KB
    float* als2   = (float*)(base + 74 * MB);                  // 200 KB
    float* ald2   = (float*)(base + 74 * MB + 512 * 1024);     // 200 KB
    unsigned short* Wt1 = (unsigned short*)(base + 75 * MB);   // 64 KB [256][128]
    unsigned short* Wt2 = (unsigned short*)(base + 75 * MB + 128 * 1024); // 32 KB
    int* counts   = (int*)(base + 76 * MB);                    // 200 KB
    int* state    = counts + N_NODES;                          // 3 ints (memset w/ counts)
    int* rowptr   = (int*)(base + 77 * MB);                    // 200 KB + 4 B
    int* bsum     = (int*)(base + 78 * MB);                    // small
    int* boff     = bsum + 256;
    unsigned* flag = (unsigned*)(base + 78 * MB + 8 * 1024);
    int* epos     = (int*)(base + 79 * MB);                    // 2.76 MB
    int* ecsr     = (int*)(base + 82 * MB);                    // 2.76 MB (exact)

    const int BLK = 256;
    const int node_wave_blocks = (N_NODES * 64 + BLK - 1) / BLK;  // 12500

    // 1. zero counts + state (single async memset, graph-capture safe)
    hipMemsetAsync(counts, 0, (size_t)N_NODES * 4 + 12, stream);

    // 2. conv (x16, Wt1, Wt2; inline dtype probe) || count edges (slot in epos)
    conv_count<<<CONVB + EDGEB, BLK, 0, stream>>>(
        x, W1, W2, flag, x16, Wt1, Wt2, edst, counts, epos);

    // 3. fused: scan -> rowptr || layer-1 GEMM (64x128 tiles) || fill_csr
    gemm1_scan_fill<<<SCAN_NBLK + G1B + EDGEB, BLK, 0, stream>>>(
        counts, rowptr, bsum, boff, state, x16, Wt1, as1, ad1, flag,
        h16, als1, ald1, esrc, edst, epos, ecsr);

    // 4. layer-1 aggregate
    agg_node1<<<node_wave_blocks, BLK, 0, stream>>>(
        rowptr, ecsr, h16, als1, ald1, b1, flag, xo16);

    // 5. layer-2 GEMM
    gemm2<<<MT, BLK, 0, stream>>>(xo16, Wt2, as2, ad2, flag, h2, als2, ald2);

    // 6. layer-2 aggregate -> out
    agg_node2<<<node_wave_blocks, BLK, 0, stream>>>(
        rowptr, ecsr, h2, als2, ald2, b2, flag, out);
}

// Round 6
// 293.741 us; speedup vs baseline: 1.1004x; 1.0103x over previous
//
#include <hip/hip_runtime.h>
#include <hip/hip_bf16.h>
#include <cstdint>
#include <cstddef>

#define N_NODES 50000
#define N_EDGES 640000
#define ET (N_EDGES + N_NODES)   // 690000 with self loops
#define IN_CH 128
#define H1 4
#define HC1 256                  // H1*C1
#define OUT_CH 64
#define SLOPE 0.2f
#define SCAN_NBLK ((N_NODES + 255) / 256)   // 196
#define XW (N_NODES * IN_CH / 8)            // 800000
#define W1N (IN_CH * HC1)                   // 32768
#define W2N (HC1 * OUT_CH)                  // 16384
#define CONVB ((XW + W1N + W2N + 255) / 256)  // 3317
#define EDGEB ((ET + 255) / 256)            // 2696
#define MT ((N_NODES + 63) / 64)            // 782
#define G1B (4 * MT)                        // 3128: NSUB=4 tiles (64x64, B L1-resident)

typedef __attribute__((ext_vector_type(8))) short short8;
typedef __attribute__((ext_vector_type(4))) float floatx4;

__device__ __forceinline__ float bf2f(unsigned short u) {
    return __uint_as_float(((unsigned)u) << 16);
}
__device__ __forceinline__ unsigned short f2bf(float f) {
    unsigned u = __float_as_uint(f);
    unsigned r = 0x7fffu + ((u >> 16) & 1u);
    return (unsigned short)((u + r) >> 16);
}
__device__ __forceinline__ float ldf(const void* p, size_t i, bool f32) {
    return f32 ? ((const float*)p)[i] : bf2f(((const unsigned short*)p)[i]);
}
#define BLO(u) __uint_as_float((u) << 16)
#define BHI(u) __uint_as_float((u) & 0xffff0000u)

// x dtype probe: every wave checks x[0..255] interpreted as bf16; garbage/huge
// values mean the buffer is really f32. Wave-uniform, no global dependency.
__device__ __forceinline__ bool probe_f32(const unsigned short* x) {
    int t = threadIdx.x & 63;
    int bad = 0;
    #pragma unroll
    for (int r = 0; r < 4; ++r) {
        float v = bf2f(x[r * 64 + t]);
        if (!(v == v) || fabsf(v) > 1e4f) bad = 1;
    }
    unsigned long long m = __ballot(bad != 0);
    return m != 0ull;
}

// ------- conv (x->bf16, W1^T, W2^T) || count edges (+record slot) ------------
// dtype detect folded in: each block probes locally; block 0 publishes flag.
__global__ __launch_bounds__(256) void conv_count(
    const void* __restrict__ x, const void* __restrict__ W1,
    const void* __restrict__ W2, unsigned* __restrict__ flag,
    unsigned short* __restrict__ x16,
    unsigned short* __restrict__ Wt1, unsigned short* __restrict__ Wt2,
    const int* __restrict__ edst, int* __restrict__ counts,
    int* __restrict__ epos)
{
    int b = blockIdx.x;
    if (b < CONVB) {
        const bool f32 = probe_f32((const unsigned short*)x);
        if (b == 0 && threadIdx.x == 0) *flag = f32 ? 1u : 0u;
        int i = b * 256 + threadIdx.x;
        if (i < XW) {
            size_t off = (size_t)i * 8;
            uint4 st;
            if (f32) {
                const float* xp = (const float*)x + off;
                float4 a = *(const float4*)xp;
                float4 c = *(const float4*)(xp + 4);
                st.x = (unsigned)f2bf(a.x) | ((unsigned)f2bf(a.y) << 16);
                st.y = (unsigned)f2bf(a.z) | ((unsigned)f2bf(a.w) << 16);
                st.z = (unsigned)f2bf(c.x) | ((unsigned)f2bf(c.y) << 16);
                st.w = (unsigned)f2bf(c.z) | ((unsigned)f2bf(c.w) << 16);
            } else {
                st = *(const uint4*)((const unsigned short*)x + off);
            }
            *(uint4*)(x16 + off) = st;
        } else if (i < XW + W1N) {
            int j = i - XW;                       // Wt1[n][k] = W1[k][n]
            int n = j / IN_CH, k = j % IN_CH;
            Wt1[j] = f2bf(ldf(W1, (size_t)k * HC1 + n, f32));
        } else if (i < XW + W1N + W2N) {
            int j = i - XW - W1N;                 // Wt2[n][k] = W2[k][n]
            int n = j / HC1, k = j % HC1;
            Wt2[j] = f2bf(ldf(W2, (size_t)k * OUT_CH + n, f32));
        }
    } else {
        int i = (b - CONVB) * 256 + threadIdx.x;
        if (i < ET) {
            int d = (i < N_EDGES) ? edst[i] : (i - N_EDGES);
            epos[i] = atomicAdd(&counts[d], 1);   // slot within bucket
        }
    }
}

// ---------------- single-dispatch two-phase scan (exact counts) --------------
__global__ __launch_bounds__(256) void scan_onepass(
    const int* __restrict__ counts, int* __restrict__ rowptr,
    int* __restrict__ bsum, int* __restrict__ boff, int* __restrict__ state)
{
    __shared__ int s[256];
    const int t = threadIdx.x, b = blockIdx.x;
    const int i = b * 256 + t;
    int v = (i < N_NODES) ? counts[i] : 0;
    s[t] = v;
    __syncthreads();
    #pragma unroll
    for (int off = 1; off < 256; off <<= 1) {
        int u = (t >= off) ? s[t - off] : 0;
        __syncthreads();
        s[t] += u;
        __syncthreads();
    }
    const int incl = s[t];
    if (t == 255) {
        __hip_atomic_store(&bsum[b], incl, __ATOMIC_RELAXED, __HIP_MEMORY_SCOPE_AGENT);
        __hip_atomic_fetch_add(&state[0], 1, __ATOMIC_ACQ_REL, __HIP_MEMORY_SCOPE_AGENT);
    }
    if (b == 0) {
        if (t == 0) {
            while (__hip_atomic_load(&state[0], __ATOMIC_ACQUIRE, __HIP_MEMORY_SCOPE_AGENT) < SCAN_NBLK)
                __builtin_amdgcn_s_sleep(8);
        }
        __syncthreads();
        int w = (t < SCAN_NBLK)
              ? __hip_atomic_load(&bsum[t], __ATOMIC_RELAXED, __HIP_MEMORY_SCOPE_AGENT) : 0;
        s[t] = w;
        __syncthreads();
        #pragma unroll
        for (int off = 1; off < 256; off <<= 1) {
            int u = (t >= off) ? s[t - off] : 0;
            __syncthreads();
            s[t] += u;
            __syncthreads();
        }
        if (t < SCAN_NBLK)
            __hip_atomic_store(&boff[t], s[t] - w, __ATOMIC_RELAXED, __HIP_MEMORY_SCOPE_AGENT);
        __syncthreads();
        if (t == 0)
            __hip_atomic_store(&state[1], 1, __ATOMIC_RELEASE, __HIP_MEMORY_SCOPE_AGENT);
    }
    if (t == 0) {
        while (__hip_atomic_load(&state[1], __ATOMIC_ACQUIRE, __HIP_MEMORY_SCOPE_AGENT) == 0)
            __builtin_amdgcn_s_sleep(8);
    }
    __syncthreads();
    int off0 = __hip_atomic_load(&boff[b], __ATOMIC_RELAXED, __HIP_MEMORY_SCOPE_AGENT);
    if (i < N_NODES)
        rowptr[i] = off0 + incl - v;   // exclusive
    if (i == N_NODES - 1) rowptr[N_NODES] = off0 + incl;   // == ET
}

// ---------------- MFMA bf16 GEMM body (NSUB=4: 16 KB B slice, L1-resident) ---
template <int KK, int NSUB>
__device__ __forceinline__ void gemm_body(
    const unsigned short* __restrict__ A, const unsigned short* __restrict__ Bt,
    const void* __restrict__ avs, const void* __restrict__ avd,
    const unsigned* __restrict__ flag, unsigned short* __restrict__ C,
    float* __restrict__ als, float* __restrict__ ald,
    int M, int N, int bx, int by)
{
    const int tid = threadIdx.x;
    const int m0 = by * 64, n0 = bx * (NSUB * 16);
    const int w = tid >> 6, lane = tid & 63;
    const int ln = lane & 15, quad = lane >> 4;
    const int m_frag = m0 + w * 16 + ln;
    floatx4 acc[NSUB];
    #pragma unroll
    for (int sub = 0; sub < NSUB; ++sub)
        acc[sub] = (floatx4){0.f, 0.f, 0.f, 0.f};

    for (int ks = 0; ks < KK / 32; ++ks) {
        const int kbase = ks * 32 + quad * 8;
        short8 a;
        if (m_frag < M) {
            a = *(const short8*)(A + (size_t)m_frag * KK + kbase);
        } else {
            #pragma unroll
            for (int j = 0; j < 8; ++j) a[j] = 0;
        }
        #pragma unroll
        for (int sub = 0; sub < NSUB; ++sub) {
            short8 b = *(const short8*)(Bt + (size_t)(n0 + sub * 16 + ln) * KK + kbase);
            acc[sub] = __builtin_amdgcn_mfma_f32_16x16x32_bf16(a, b, acc[sub], 0, 0, 0);
        }
    }

    #pragma unroll
    for (int sub = 0; sub < NSUB; ++sub) {
        #pragma unroll
        for (int r = 0; r < 4; ++r) {
            int m = m0 + w * 16 + quad * 4 + r;
            if (m < M)
                C[(size_t)m * N + n0 + sub * 16 + ln] = f2bf(acc[sub][r]);
        }
    }

    const bool f32in = (*flag != 0);
    float as[NSUB], av[NSUB];
    #pragma unroll
    for (int sub = 0; sub < NSUB; ++sub) {
        as[sub] = ldf(avs, n0 + sub * 16 + ln, f32in);
        av[sub] = ldf(avd, n0 + sub * 16 + ln, f32in);
    }
    const int Hh = N >> 6;
    #pragma unroll
    for (int hb = 0; hb < NSUB / 4; ++hb) {
        #pragma unroll
        for (int r = 0; r < 4; ++r) {
            float ps = 0.f, pd = 0.f;
            #pragma unroll
            for (int k = 0; k < 4; ++k) {
                ps += acc[hb * 4 + k][r] * as[hb * 4 + k];
                pd += acc[hb * 4 + k][r] * av[hb * 4 + k];
            }
            #pragma unroll
            for (int off = 1; off < 16; off <<= 1) {
                ps += __shfl_xor(ps, off, 64);
                pd += __shfl_xor(pd, off, 64);
            }
            int m = m0 + w * 16 + quad * 4 + r;
            if (ln == 0 && m < M) {
                als[(size_t)m * Hh + bx * (NSUB / 4) + hb] = ps;
                ald[(size_t)m * Hh + bx * (NSUB / 4) + hb] = pd;
            }
        }
    }
}

// -------- layer-1 GEMM (64x64 tiles) || fill_csr (atomic-free) ---------------
__global__ __launch_bounds__(256) void gemm1_fill(
    const unsigned short* __restrict__ x16, const unsigned short* __restrict__ Wt1,
    const void* __restrict__ as1, const void* __restrict__ ad1,
    const unsigned* __restrict__ flag, unsigned short* __restrict__ h16,
    float* __restrict__ als, float* __restrict__ ald,
    const int* __restrict__ esrc, const int* __restrict__ edst,
    const int* __restrict__ rowptr, const int* __restrict__ epos,
    int* __restrict__ ecsr)
{
    int b = blockIdx.x;
    if (b < G1B) {
        gemm_body<IN_CH, 4>(x16, Wt1, as1, ad1, flag, h16, als, ald,
                            N_NODES, HC1, b & 3, b >> 2);
    } else {
        int i = (b - G1B) * 256 + threadIdx.x;
        if (i < ET) {
            int s = (i < N_EDGES) ? esrc[i] : (i - N_EDGES);
            int d = (i < N_EDGES) ? edst[i] : (i - N_EDGES);
            ecsr[rowptr[d] + epos[i]] = s;   // no atomic: slot recorded in count
        }
    }
}

// ------- fused softmax + gather-aggregate, layer 1 (H=4) ---------------------
// 8-wide unrolled, clamped indices + p=0 select: 8 row gathers in flight per
// wave, zero padding, exact result (duplicate rows weighted 0).
__global__ __launch_bounds__(256) void agg_node1(
    const int* __restrict__ rowptr, const int* __restrict__ ecsr,
    const unsigned short* __restrict__ h, const float* __restrict__ als,
    const float* __restrict__ ald, const void* __restrict__ bias,
    const unsigned* __restrict__ flag, unsigned short* __restrict__ out)
{
    int wave = (blockIdx.x * blockDim.x + threadIdx.x) >> 6;
    int lane = threadIdx.x & 63;
    if (wave >= N_NODES) return;
    const int d = wave;
    const int hg = lane >> 4;          // head
    const int c0 = (lane & 15) << 2;   // channel base (4 channels)
    const int hoff = hg * 64 + c0;
    const int lo = rowptr[d], hi = rowptr[d + 1];   // hi > lo (self loop)
    const float ad = ald[d * H1 + hg];

    float acc0 = 0.f, acc1 = 0.f, acc2 = 0.f, acc3 = 0.f, den = 0.f;

    for (int e = lo; e < hi; e += 8) {
        int e1 = min(e + 1, hi - 1), e2 = min(e + 2, hi - 1);
        int e3 = min(e + 3, hi - 1), e4 = min(e + 4, hi - 1);
        int e5 = min(e + 5, hi - 1), e6 = min(e + 6, hi - 1);
        int e7 = min(e + 7, hi - 1);
        int s0 = ecsr[e],  s1 = ecsr[e1], s2 = ecsr[e2], s3 = ecsr[e3];
        int s4 = ecsr[e4], s5 = ecsr[e5], s6 = ecsr[e6], s7 = ecsr[e7];
        uint2 q0 = *(const uint2*)(h + (size_t)s0 * HC1 + hoff);
        uint2 q1 = *(const uint2*)(h + (size_t)s1 * HC1 + hoff);
        uint2 q2 = *(const uint2*)(h + (size_t)s2 * HC1 + hoff);
        uint2 q3 = *(const uint2*)(h + (size_t)s3 * HC1 + hoff);
        uint2 q4 = *(const uint2*)(h + (size_t)s4 * HC1 + hoff);
        uint2 q5 = *(const uint2*)(h + (size_t)s5 * HC1 + hoff);
        uint2 q6 = *(const uint2*)(h + (size_t)s6 * HC1 + hoff);
        uint2 q7 = *(const uint2*)(h + (size_t)s7 * HC1 + hoff);
        float t0 = als[s0 * H1 + hg] + ad;
        float t1 = als[s1 * H1 + hg] + ad;
        float t2 = als[s2 * H1 + hg] + ad;
        float t3 = als[s3 * H1 + hg] + ad;
        float t4 = als[s4 * H1 + hg] + ad;
        float t5 = als[s5 * H1 + hg] + ad;
        float t6 = als[s6 * H1 + hg] + ad;
        float t7 = als[s7 * H1 + hg] + ad;
        float p0 = __expf(fmaxf(t0, SLOPE * t0));
        float p1 = (e + 1 < hi) ? __expf(fmaxf(t1, SLOPE * t1)) : 0.f;
        float p2 = (e + 2 < hi) ? __expf(fmaxf(t2, SLOPE * t2)) : 0.f;
        float p3 = (e + 3 < hi) ? __expf(fmaxf(t3, SLOPE * t3)) : 0.f;
        float p4 = (e + 4 < hi) ? __expf(fmaxf(t4, SLOPE * t4)) : 0.f;
        float p5 = (e + 5 < hi) ? __expf(fmaxf(t5, SLOPE * t5)) : 0.f;
        float p6 = (e + 6 < hi) ? __expf(fmaxf(t6, SLOPE * t6)) : 0.f;
        float p7 = (e + 7 < hi) ? __expf(fmaxf(t7, SLOPE * t7)) : 0.f;
        den += ((p0 + p1) + (p2 + p3)) + ((p4 + p5) + (p6 + p7));
        acc0 += p0 * BLO(q0.x) + p1 * BLO(q1.x) + p2 * BLO(q2.x) + p3 * BLO(q3.x)
              + p4 * BLO(q4.x) + p5 * BLO(q5.x) + p6 * BLO(q6.x) + p7 * BLO(q7.x);
        acc1 += p0 * BHI(q0.x) + p1 * BHI(q1.x) + p2 * BHI(q2.x) + p3 * BHI(q3.x)
              + p4 * BHI(q4.x) + p5 * BHI(q5.x) + p6 * BHI(q6.x) + p7 * BHI(q7.x);
        acc2 += p0 * BLO(q0.y) + p1 * BLO(q1.y) + p2 * BLO(q2.y) + p3 * BLO(q3.y)
              + p4 * BLO(q4.y) + p5 * BLO(q5.y) + p6 * BLO(q6.y) + p7 * BLO(q7.y);
        acc3 += p0 * BHI(q0.y) + p1 * BHI(q1.y) + p2 * BHI(q2.y) + p3 * BHI(q3.y)
              + p4 * BHI(q4.y) + p5 * BHI(q5.y) + p6 * BHI(q6.y) + p7 * BHI(q7.y);
    }

    const bool f32in = (*flag != 0);
    const float inv = 1.f / den;
    float v0 = acc0 * inv + ldf(bias, hoff + 0, f32in);
    float v1 = acc1 * inv + ldf(bias, hoff + 1, f32in);
    float v2 = acc2 * inv + ldf(bias, hoff + 2, f32in);
    float v3 = acc3 * inv + ldf(bias, hoff + 3, f32in);
    v0 = (v0 > 0.f) ? v0 : (__expf(v0) - 1.f);
    v1 = (v1 > 0.f) ? v1 : (__expf(v1) - 1.f);
    v2 = (v2 > 0.f) ? v2 : (__expf(v2) - 1.f);
    v3 = (v3 > 0.f) ? v3 : (__expf(v3) - 1.f);
    uint2 st;
    st.x = (unsigned)f2bf(v0) | ((unsigned)f2bf(v1) << 16);
    st.y = (unsigned)f2bf(v2) | ((unsigned)f2bf(v3) << 16);
    *(uint2*)(out + (size_t)d * HC1 + hoff) = st;
}

// ---------------- layer-2 GEMM ----------------
__global__ __launch_bounds__(256) void gemm2(
    const unsigned short* __restrict__ xo16, const unsigned short* __restrict__ Wt2,
    const void* __restrict__ as2, const void* __restrict__ ad2,
    const unsigned* __restrict__ flag, unsigned short* __restrict__ h2,
    float* __restrict__ als, float* __restrict__ ald)
{
    gemm_body<HC1, 4>(xo16, Wt2, as2, ad2, flag, h2, als, ald,
                      N_NODES, OUT_CH, 0, blockIdx.x);
}

// ------- fused softmax + gather-aggregate, layer 2 (H=1): R0 proven form -----
__global__ __launch_bounds__(256) void agg_node2(
    const int* __restrict__ rowptr, const int* __restrict__ ecsr,
    const unsigned short* __restrict__ h, const float* __restrict__ als,
    const float* __restrict__ ald, const void* __restrict__ bias,
    const unsigned* __restrict__ flag, float* __restrict__ out)
{
    int wave = (blockIdx.x * blockDim.x + threadIdx.x) >> 6;
    int lane = threadIdx.x & 63;
    if (wave >= N_NODES) return;
    const int d = wave;
    const int eg = lane >> 3;          // edge slot 0..7
    const int c0 = (lane & 7) << 3;    // channel base (8 channels)
    const int lo = rowptr[d], hi = rowptr[d + 1];
    const float ad = ald[d];

    float acc[8];
    #pragma unroll
    for (int j = 0; j < 8; ++j) acc[j] = 0.f;
    float den = 0.f;

    for (int eb = lo; eb < hi; eb += 8) {
        int e = eb + eg;
        if (e < hi) {
            int s = ecsr[e];
            uint4 q = *(const uint4*)(h + (size_t)s * OUT_CH + c0);
            float t = als[s] + ad;
            float p = __expf(fmaxf(t, SLOPE * t));
            den += p;
            acc[0] += p * BLO(q.x);
            acc[1] += p * BHI(q.x);
            acc[2] += p * BLO(q.y);
            acc[3] += p * BHI(q.y);
            acc[4] += p * BLO(q.z);
            acc[5] += p * BHI(q.z);
            acc[6] += p * BLO(q.w);
            acc[7] += p * BHI(q.w);
        }
    }
    #pragma unroll
    for (int off = 8; off <= 32; off <<= 1) {
        den += __shfl_xor(den, off, 64);
        #pragma unroll
        for (int j = 0; j < 8; ++j) acc[j] += __shfl_xor(acc[j], off, 64);
    }
    if (lane < 8) {
        const bool f32in = (*flag != 0);
        const float inv = 1.f / den;
        float4 v0, v1;
        v0.x = acc[0] * inv + ldf(bias, c0 + 0, f32in);
        v0.y = acc[1] * inv + ldf(bias, c0 + 1, f32in);
        v0.z = acc[2] * inv + ldf(bias, c0 + 2, f32in);
        v0.w = acc[3] * inv + ldf(bias, c0 + 3, f32in);
        v1.x = acc[4] * inv + ldf(bias, c0 + 4, f32in);
        v1.y = acc[5] * inv + ldf(bias, c0 + 5, f32in);
        v1.z = acc[6] * inv + ldf(bias, c0 + 6, f32in);
        v1.w = acc[7] * inv + ldf(bias, c0 + 7, f32in);
        *(float4*)(out + (size_t)d * OUT_CH + c0) = v0;
        *(float4*)(out + (size_t)d * OUT_CH + c0 + 4) = v1;
    }
}

extern "C" void kernel_launch(void* const* d_in, const int* in_sizes, int n_in,
                              void* d_out, int out_size, void* d_ws, size_t ws_size,
                              hipStream_t stream)
{
    const void* x   = d_in[0];
    const void* W1  = d_in[1];
    const void* as1 = d_in[2];
    const void* ad1 = d_in[3];
    const void* b1  = d_in[4];
    const void* W2  = d_in[5];
    const void* as2 = d_in[6];
    const void* ad2 = d_in[7];
    const void* b2  = d_in[8];
    const int* esrc = (const int*)d_in[9];
    const int* edst = (const int*)d_in[10];
    float* out = (float*)d_out;  // [N,64] float32

    char* base = (char*)d_ws;
    const size_t MB = 1024 * 1024;
    unsigned short* x16  = (unsigned short*)(base);            // 12.8 MB [N,128] bf16
    unsigned short* h16  = (unsigned short*)(base + 13 * MB);  // 25.6 MB h1 [N,256] bf16
    unsigned short* xo16 = (unsigned short*)(base + 39 * MB);  // 25.6 MB x2 [N,256] bf16
    unsigned short* h2   = (unsigned short*)(base + 65 * MB);  //  6.4 MB h2 [N,64] bf16
    float* als1   = (float*)(base + 72 * MB);                  // 800 KB
    float* ald1   = (float*)(base + 73 * MB);                  // 800 KB
    float* als2   = (float*)(base + 74 * MB);                  // 200 KB
    float* ald2   = (float*)(base + 74 * MB + 512 * 1024);     // 200 KB
    unsigned short* Wt1 = (unsigned short*)(base + 75 * MB);   // 64 KB [256][128]
    unsigned short* Wt2 = (unsigned short*)(base + 75 * MB + 128 * 1024); // 32 KB
    int* counts   = (int*)(base + 76 * MB);                    // 200 KB
    int* state    = counts + N_NODES;                          // 3 ints (memset w/ counts)
    int* rowptr   = (int*)(base + 77 * MB);                    // 200 KB + 4 B
    int* bsum     = (int*)(base + 78 * MB);                    // small
    int* boff     = bsum + 256;
    unsigned* flag = (unsigned*)(base + 78 * MB + 8 * 1024);
    int* epos     = (int*)(base + 79 * MB);                    // 2.76 MB
    int* ecsr     = (int*)(base + 82 * MB);                    // 2.76 MB (exact)

    const int BLK = 256;
    const int node_wave_blocks = (N_NODES * 64 + BLK - 1) / BLK;  // 12500

    // 1. zero counts + state (single async memset, graph-capture safe)
    hipMemsetAsync(counts, 0, (size_t)N_NODES * 4 + 12, stream);

    // 2. conv (x16, Wt1, Wt2; inline dtype probe) || count edges (slot in epos)
    conv_count<<<CONVB + EDGEB, BLK, 0, stream>>>(
        x, W1, W2, flag, x16, Wt1, Wt2, edst, counts, epos);

    // 3. single-dispatch scan (exact counts) -> rowptr
    scan_onepass<<<SCAN_NBLK, BLK, 0, stream>>>(
        counts, rowptr, bsum, boff, state);

    // 4. layer-1 GEMM (64x64 tiles, B L1-resident) || fill_csr
    gemm1_fill<<<G1B + EDGEB, BLK, 0, stream>>>(
        x16, Wt1, as1, ad1, flag, h16, als1, ald1, esrc, edst, rowptr, epos,
        ecsr);

    // 5. layer-1 aggregate (8-wide clamped)
    agg_node1<<<node_wave_blocks, BLK, 0, stream>>>(
        rowptr, ecsr, h16, als1, ald1, b1, flag, xo16);

    // 6. layer-2 GEMM
    gemm2<<<MT, BLK, 0, stream>>>(xo16, Wt2, as2, ad2, flag, h2, als2, ald2);

    // 7. layer-2 aggregate -> out
    agg_node2<<<node_wave_blocks, BLK, 0, stream>>>(
        rowptr, ecsr, h2, als2, ald2, b2, flag, out);
}